// Round 6
// baseline (874.459 us; speedup 1.0000x reference)
//
#include <hip/hip_runtime.h>
#include <hip/hip_fp16.h>

// ---------------- problem constants ----------------
constexpr int   NN   = 100000;      // nodes
constexpr int   NE   = 3200000;     // edges
constexpr float BN_EPS = 1e-5f;

typedef _Float16 half8 __attribute__((ext_vector_type(8)));
typedef float    floatx16 __attribute__((ext_vector_type(16)));

// ============================================================
// CSR build: byte-packed count(+slot) -> scan -> fill
// Max degree ~59 << 255, so 4 per-node counters pack into one u32:
// 4x fewer dirty lines at the coherence point (WRITE_SIZE was the cap).
// ============================================================
__global__ __launch_bounds__(256) void k_count(const int* __restrict__ dst,
                                               unsigned* __restrict__ degp,
                                               int* __restrict__ slot) {
  int e = blockIdx.x * 256 + threadIdx.x;
  if (e >= NE) return;
  int d = dst[e];
  unsigned sh = (d & 3) * 8;
  unsigned old = atomicAdd(&degp[d >> 2], 1u << sh);
  slot[e] = (old >> sh) & 0xFF;
}

__global__ __launch_bounds__(256) void k_scan_a(const unsigned* __restrict__ degp,
                                                float* __restrict__ dinv,
                                                int* __restrict__ rowptr,
                                                int* __restrict__ bsum) {
  __shared__ int sd[256];
  int t = threadIdx.x;
  int i = blockIdx.x * 256 + t;
  int v = (i < NN) ? (int)((degp[i >> 2] >> (8 * (i & 3))) & 0xFF) : 0;
  if (i < NN) dinv[i] = rsqrtf((float)(v + 1));   // +1 self-loop
  sd[t] = v;
  __syncthreads();
  for (int off = 1; off < 256; off <<= 1) {
    int x = (t >= off) ? sd[t - off] : 0;
    __syncthreads();
    sd[t] += x;
    __syncthreads();
  }
  if (i < NN) rowptr[i] = sd[t] - v;              // exclusive
  if (t == 255) bsum[blockIdx.x] = sd[255];
}

__global__ __launch_bounds__(512) void k_scan_b(int* __restrict__ bsum, int nb) {
  __shared__ int sd[512];
  int t = threadIdx.x;
  int v = (t < nb) ? bsum[t] : 0;
  sd[t] = v;
  __syncthreads();
  for (int off = 1; off < 512; off <<= 1) {
    int x = (t >= off) ? sd[t - off] : 0;
    __syncthreads();
    sd[t] += x;
    __syncthreads();
  }
  if (t < nb) bsum[t] = sd[t] - v;                // exclusive block offsets
}

__global__ __launch_bounds__(256) void k_scan_c(int* __restrict__ rowptr,
                                                const int* __restrict__ bsum) {
  int i = blockIdx.x * 256 + threadIdx.x;
  if (i < NN) rowptr[i] += bsum[blockIdx.x];
  if (i == 0) rowptr[NN] = NE;
}

__global__ __launch_bounds__(256) void k_fill(const int* __restrict__ ei,
                                              const int* __restrict__ rowptr,
                                              const int* __restrict__ slot,
                                              int* __restrict__ csrc) {
  int e = blockIdx.x * 256 + threadIdx.x;
  if (e >= NE) return;
  int s = ei[e];            // edge_index[0] = src
  int d = ei[NE + e];       // edge_index[1] = dst
  csrc[rowptr[d] + slot[e]] = s;
}

// ============================================================
// Weight prep: Wt[n][k] = fp16(W[k][n])  (transpose + cast, tiny)
// ============================================================
template <int BN_>
__global__ __launch_bounds__(256) void k_wprep(const float* __restrict__ W,
                                               _Float16* __restrict__ Wt) {
  int idx = blockIdx.x * 256 + threadIdx.x;
  if (idx >= 128 * BN_) return;
  int k = idx / BN_, n = idx % BN_;
  Wt[n * 128 + k] = (_Float16)W[idx];
}

// ============================================================
// MFMA f16 GEMM (register-only, no LDS):
// Ht[r,:] = fp16( dinv[r] * ( act(A[r,:]) @ W ) ), K=128, BN_ cols.
// One wave = 32 rows x BN_ cols. v_mfma_f32_32x32x16_f16:
//   A-frag: A[m=lane&31][k=(lane>>5)*8+j], j=0..7 (half8)
//   B-frag: B[k][n=lane&31] == Wt[n][k] contiguous
//   C/D:    col=lane&31, row=(reg&3)+8*(reg>>2)+4*(lane>>5)  [m74/m101]
// AT = float (layer 1, no BN) or _Float16 (layers 2,3 + fused BN/ReLU).
// ============================================================
template <int BN_, bool FUSE_BN, typename AT>
__global__ __launch_bounds__(256) void k_mgemm(const AT* __restrict__ A,
                                               const _Float16* __restrict__ Wt,
                                               const float* __restrict__ scale,
                                               const float* __restrict__ shift,
                                               const float* __restrict__ dinv,
                                               _Float16* __restrict__ C) {
  constexpr int NCT = BN_ / 32;       // col tiles per wave
  int wid  = (blockIdx.x * 256 + threadIdx.x) >> 6;   // wave id = 32-row block
  int lane = threadIdx.x & 63;
  if (wid >= NN / 32) return;                         // 3125 waves exactly
  const int m = lane & 31;
  const int q = lane >> 5;
  const int row0 = wid * 32;

  const AT* Arow = A + (size_t)(row0 + m) * 128 + q * 8;

  floatx16 acc[NCT] = {};

#pragma unroll
  for (int s = 0; s < 8; ++s) {       // K = 8 steps x 16
    float av[8];
    if constexpr (__is_same(AT, float)) {
      float4 a0 = *(const float4*)(Arow + 16 * s);
      float4 a1 = *(const float4*)(Arow + 16 * s + 4);
      av[0] = a0.x; av[1] = a0.y; av[2] = a0.z; av[3] = a0.w;
      av[4] = a1.x; av[5] = a1.y; av[6] = a1.z; av[7] = a1.w;
    } else {
      half8 raw = *(const half8*)(Arow + 16 * s);
#pragma unroll
      for (int j = 0; j < 8; ++j) av[j] = (float)raw[j];
    }
    if (FUSE_BN) {
      int k0 = 16 * s + q * 8;
#pragma unroll
      for (int j = 0; j < 8; ++j)
        av[j] = fmaxf(fmaf(av[j], scale[k0 + j], shift[k0 + j]), 0.f);
    }
    half8 af;
#pragma unroll
    for (int j = 0; j < 8; ++j) af[j] = (_Float16)av[j];
#pragma unroll
    for (int ct = 0; ct < NCT; ++ct) {
      half8 bf = *(const half8*)(Wt + (size_t)(ct * 32 + m) * 128 + q * 8 + 16 * s);
      acc[ct] = __builtin_amdgcn_mfma_f32_32x32x16_f16(af, bf, acc[ct], 0, 0, 0);
    }
  }

  // epilogue: scale rows by dinv, cast to fp16, store
#pragma unroll
  for (int ct = 0; ct < NCT; ++ct) {
#pragma unroll
    for (int r = 0; r < 16; ++r) {
      int row = (r & 3) + 8 * (r >> 2) + 4 * q;
      float dv = dinv[row0 + row];
      C[(size_t)(row0 + row) * BN_ + ct * 32 + m] = (_Float16)(acc[ct][r] * dv);
    }
  }
}

// ============================================================
// Pull aggregation, D=128 fp16 table -> fp16 out:
// out[i] = dinv_i * (Ht[i] + sum_j Ht[s_j]); one wave per node.
// fp32 accumulate, fp16 store (h is renormalized by BN downstream).
// ============================================================
__global__ __launch_bounds__(256) void k_agg128(const __half* __restrict__ H,
                                                const float* __restrict__ dinv,
                                                const int* __restrict__ rowptr,
                                                const int* __restrict__ srcs,
                                                __half2* __restrict__ out) {
  int wid  = (blockIdx.x * 256 + threadIdx.x) >> 6;
  int lane = threadIdx.x & 63;
  if (wid >= NN) return;
  const __half2* Hp = (const __half2*)H;
  float2 acc = __half22float2(Hp[(size_t)wid * 64 + lane]);   // self term
  int beg = rowptr[wid], end = rowptr[wid + 1];
  int e = beg;
  int end8 = beg + ((end - beg) & ~7);
  for (; e < end8; e += 8) {
    __half2 v0 = Hp[(size_t)srcs[e+0] * 64 + lane];
    __half2 v1 = Hp[(size_t)srcs[e+1] * 64 + lane];
    __half2 v2 = Hp[(size_t)srcs[e+2] * 64 + lane];
    __half2 v3 = Hp[(size_t)srcs[e+3] * 64 + lane];
    __half2 v4 = Hp[(size_t)srcs[e+4] * 64 + lane];
    __half2 v5 = Hp[(size_t)srcs[e+5] * 64 + lane];
    __half2 v6 = Hp[(size_t)srcs[e+6] * 64 + lane];
    __half2 v7 = Hp[(size_t)srcs[e+7] * 64 + lane];
    float2 f0 = __half22float2(v0), f1 = __half22float2(v1);
    float2 f2 = __half22float2(v2), f3 = __half22float2(v3);
    float2 f4 = __half22float2(v4), f5 = __half22float2(v5);
    float2 f6 = __half22float2(v6), f7 = __half22float2(v7);
    acc.x += (f0.x + f1.x) + (f2.x + f3.x) + (f4.x + f5.x) + (f6.x + f7.x);
    acc.y += (f0.y + f1.y) + (f2.y + f3.y) + (f4.y + f5.y) + (f6.y + f7.y);
  }
  for (; e < end; ++e) {
    float2 f = __half22float2(Hp[(size_t)srcs[e] * 64 + lane]);
    acc.x += f.x; acc.y += f.y;
  }
  float di = dinv[wid];
  out[(size_t)wid * 64 + lane] = __floats2half2_rn(acc.x * di, acc.y * di);
}

// ============================================================
// Final layer: aggregation (D=64, fp16 table) + bias + softmax
// ============================================================
__global__ __launch_bounds__(256) void k_agg64_softmax(const __half* __restrict__ H,
                                                       const float* __restrict__ dinv,
                                                       const int* __restrict__ rowptr,
                                                       const int* __restrict__ srcs,
                                                       const float* __restrict__ b3,
                                                       float* __restrict__ out) {
  int wid  = (blockIdx.x * 256 + threadIdx.x) >> 6;
  int lane = threadIdx.x & 63;
  if (wid >= NN) return;
  float acc = __half2float(H[(size_t)wid * 64 + lane]);   // self term
  int beg = rowptr[wid], end = rowptr[wid + 1];
  int e = beg;
  int end8 = beg + ((end - beg) & ~7);
  for (; e < end8; e += 8) {
    float v0 = __half2float(H[(size_t)srcs[e+0] * 64 + lane]);
    float v1 = __half2float(H[(size_t)srcs[e+1] * 64 + lane]);
    float v2 = __half2float(H[(size_t)srcs[e+2] * 64 + lane]);
    float v3 = __half2float(H[(size_t)srcs[e+3] * 64 + lane]);
    float v4 = __half2float(H[(size_t)srcs[e+4] * 64 + lane]);
    float v5 = __half2float(H[(size_t)srcs[e+5] * 64 + lane]);
    float v6 = __half2float(H[(size_t)srcs[e+6] * 64 + lane]);
    float v7 = __half2float(H[(size_t)srcs[e+7] * 64 + lane]);
    acc += (v0 + v1) + (v2 + v3) + (v4 + v5) + (v6 + v7);
  }
  for (; e < end; ++e)
    acc += __half2float(H[(size_t)srcs[e] * 64 + lane]);
  acc = acc * dinv[wid] + b3[lane];

  // softmax across the 64 lanes
  float m = acc;
#pragma unroll
  for (int off = 32; off > 0; off >>= 1) m = fmaxf(m, __shfl_xor(m, off));
  float ev = __expf(acc - m);
  float s = ev;
#pragma unroll
  for (int off = 32; off > 0; off >>= 1) s += __shfl_xor(s, off);
  out[(size_t)wid * 64 + lane] = ev / s;
}

// ============================================================
// BatchNorm column stats over fp16 h (fp32 accumulate)
// thread t: col pair p=t&63, row group r=t>>6 (4 groups)
// ============================================================
__global__ __launch_bounds__(256) void k_stats(const __half2* __restrict__ H2,
                                               float* __restrict__ S1,
                                               float* __restrict__ S2) {
  int t = threadIdx.x;
  int p = t & 63;
  int r = t >> 6;
  float2 s1 = {0.f, 0.f}, s2 = {0.f, 0.f};
  for (int row = blockIdx.x * 4 + r; row < NN; row += gridDim.x * 4) {
    float2 v = __half22float2(H2[(size_t)row * 64 + p]);
    s1.x += v.x; s1.y += v.y;
    s2.x += v.x * v.x; s2.y += v.y * v.y;
  }
  __shared__ float2 l1[256], l2[256];
  l1[t] = s1; l2[t] = s2;
  __syncthreads();
  if (t < 128) {
    l1[t].x += l1[t+128].x; l1[t].y += l1[t+128].y;
    l2[t].x += l2[t+128].x; l2[t].y += l2[t+128].y;
  }
  __syncthreads();
  if (t < 64) {
    float2 a1 = l1[t], b1 = l1[t+64];
    float2 a2 = l2[t], b2 = l2[t+64];
    atomicAdd(&S1[2*p+0], a1.x + b1.x);
    atomicAdd(&S1[2*p+1], a1.y + b1.y);
    atomicAdd(&S2[2*p+0], a2.x + b2.x);
    atomicAdd(&S2[2*p+1], a2.y + b2.y);
  }
}

__global__ void k_finalize(const float* __restrict__ S1, const float* __restrict__ S2,
                           const float* __restrict__ g,  const float* __restrict__ be,
                           float* __restrict__ scale,    float* __restrict__ shift) {
  int t = threadIdx.x;  // 128 threads
  float mean = S1[t] * (1.0f / NN);
  float var  = S2[t] * (1.0f / NN) - mean * mean;
  float is   = rsqrtf(var + BN_EPS);
  float sc   = g[t] * is;
  scale[t] = sc;
  shift[t] = be[t] - mean * sc;
}

// ============================================================
// host launch
// ============================================================
extern "C" void kernel_launch(void* const* d_in, const int* in_sizes, int n_in,
                              void* d_out, int out_size, void* d_ws, size_t ws_size,
                              hipStream_t stream) {
  (void)in_sizes; (void)n_in; (void)out_size; (void)ws_size;
  const float* x   = (const float*)d_in[0];
  const int*   ei  = (const int*)d_in[1];
  const float* W1  = (const float*)d_in[2];
  // d_in[3] = b1: cancels in BatchNorm (constant column shift), skipped
  const float* W2  = (const float*)d_in[4];
  // d_in[5] = b2: same
  const float* W3  = (const float*)d_in[6];
  const float* b3  = (const float*)d_in[7];
  const float* g1  = (const float*)d_in[8];
  const float* be1 = (const float*)d_in[9];
  const float* g2  = (const float*)d_in[10];
  const float* be2 = (const float*)d_in[11];
  float* out = (float*)d_out;

  char* ws = (char*)d_ws;
  size_t off = 0;
  auto take = [&](size_t bytes) -> char* {
    char* p = ws + off;
    off = (off + bytes + 255) & ~(size_t)255;
    return p;
  };
  unsigned* degp = (unsigned*)take((size_t)(NN / 4) * 4);  // byte-packed counters
  float* S1a    = (float*)take(128 * 4);
  float* S2a    = (float*)take(128 * 4);
  float* S1b    = (float*)take(128 * 4);
  float* S2b    = (float*)take(128 * 4);
  size_t zero_bytes = off;                  // degp + stats zeroed each call
  float* scale1 = (float*)take(128 * 4);
  float* shift1 = (float*)take(128 * 4);
  float* scale2 = (float*)take(128 * 4);
  float* shift2 = (float*)take(128 * 4);
  float* dinv   = (float*)take((size_t)NN * 4);
  int*   rowptr = (int*)  take((size_t)(NN + 1) * 4);
  int*   bsum   = (int*)  take(1024 * 4);
  int*   slot   = (int*)  take((size_t)NE * 4);
  int*   csrc   = (int*)  take((size_t)NE * 4);
  _Float16* Wt1 = (_Float16*)take((size_t)128 * 128 * 2);
  _Float16* Wt2 = (_Float16*)take((size_t)128 * 128 * 2);
  _Float16* Wt3 = (_Float16*)take((size_t)64 * 128 * 2);
  _Float16* Hf  = (_Float16*)take((size_t)NN * 128 * 2);  // fp16 gather table
  _Float16* hB  = (_Float16*)take((size_t)NN * 128 * 2);  // fp16 agg output

  (void)hipMemsetAsync(d_ws, 0, zero_bytes, stream);

  const int nbE = (NE + 255) / 256;
  const int nbN = (NN + 255) / 256;         // 391
  const int mgB = (NN / 32 + 3) / 4;        // 782 blocks (3125 waves)
  const int aggB  = (NN + 3) / 4;           // 25000

  k_count <<<nbE, 256, 0, stream>>>(ei + NE, degp, slot);
  k_scan_a<<<nbN, 256, 0, stream>>>(degp, dinv, rowptr, bsum);
  k_scan_b<<<1, 512, 0, stream>>>(bsum, nbN);
  k_scan_c<<<nbN, 256, 0, stream>>>(rowptr, bsum);
  k_fill  <<<nbE, 256, 0, stream>>>(ei, rowptr, slot, csrc);

  k_wprep<128><<<64, 256, 0, stream>>>(W1, Wt1);
  k_wprep<128><<<64, 256, 0, stream>>>(W2, Wt2);
  k_wprep<64> <<<32, 256, 0, stream>>>(W3, Wt3);

  // layer 1
  k_mgemm<128, false, float><<<mgB, 256, 0, stream>>>(x, Wt1, nullptr, nullptr, dinv, Hf);
  k_agg128<<<aggB, 256, 0, stream>>>((const __half*)Hf, dinv, rowptr, csrc, (__half2*)hB);
  k_stats<<<1024, 256, 0, stream>>>((const __half2*)hB, S1a, S2a);
  k_finalize<<<1, 128, 0, stream>>>(S1a, S2a, g1, be1, scale1, shift1);

  // layer 2 (BN+ReLU fused into GEMM A-load)
  k_mgemm<128, true, _Float16><<<mgB, 256, 0, stream>>>(hB, Wt2, scale1, shift1, dinv, Hf);
  k_agg128<<<aggB, 256, 0, stream>>>((const __half*)Hf, dinv, rowptr, csrc, (__half2*)hB);
  k_stats<<<1024, 256, 0, stream>>>((const __half2*)hB, S1b, S2b);
  k_finalize<<<1, 128, 0, stream>>>(S1b, S2b, g2, be2, scale2, shift2);

  // layer 3 (BN+ReLU fused) -> N x 64 fp16, then aggregation + bias + softmax
  k_mgemm<64, true, _Float16><<<mgB, 256, 0, stream>>>(hB, Wt3, scale2, shift2, dinv, Hf);
  k_agg64_softmax<<<aggB, 256, 0, stream>>>((const __half*)Hf, dinv, rowptr, csrc, b3, out);
}

// Round 7
// 837.803 us; speedup vs baseline: 1.0438x; 1.0438x over previous
//
#include <hip/hip_runtime.h>
#include <hip/hip_fp16.h>

// ---------------- problem constants ----------------
constexpr int   NN   = 100000;      // nodes
constexpr int   NE   = 3200000;     // edges
constexpr float BN_EPS = 1e-5f;

constexpr int MG_B  = (NN / 32 + 3) / 4;   // 782 mgemm blocks (3125 waves)
constexpr int CNT_B = NE / 256;            // 12500 count blocks
constexpr int SC_B  = NN * 128 / 4 / 256;  // 12500 scaleH blocks (4 halves/thread)

typedef _Float16 half8 __attribute__((ext_vector_type(8)));
typedef float    floatx16 __attribute__((ext_vector_type(16)));

// ============================================================
// Weight prep (all 3): Wt[n][k] = fp16(W[k][n])
// ============================================================
__global__ __launch_bounds__(256) void k_wprep_all(const float* __restrict__ W1,
                                                   const float* __restrict__ W2,
                                                   const float* __restrict__ W3,
                                                   _Float16* __restrict__ Wt1,
                                                   _Float16* __restrict__ Wt2,
                                                   _Float16* __restrict__ Wt3) {
  int idx = blockIdx.x * 256 + threadIdx.x;
  if (idx < 16384) {
    int k = idx >> 7, n = idx & 127;
    Wt1[n * 128 + k] = (_Float16)W1[idx];
  } else if (idx < 32768) {
    int j = idx - 16384, k = j >> 7, n = j & 127;
    Wt2[n * 128 + k] = (_Float16)W2[j];
  } else if (idx < 40960) {
    int j = idx - 32768, k = j >> 6, n = j & 63;
    Wt3[n * 128 + k] = (_Float16)W3[j];
  }
}

// ============================================================
// F1: fused  [blocks 0..MG_B)   : layer-1 MFMA GEMM (UNSCALED fp16 out)
//            [MG_B..MG_B+CNT_B) : degree count + slot capture (atomics)
// The count path is coherence-point-bound (0.6% VALU), so mgemm
// co-residency is ~free; mgemm blocks first to grab CUs immediately.
// ============================================================
__global__ __launch_bounds__(256) void k_f1(const int* __restrict__ dst,
                                            int* __restrict__ deg,
                                            int* __restrict__ slot,
                                            const float* __restrict__ x,
                                            const _Float16* __restrict__ Wt1,
                                            _Float16* __restrict__ C) {
  if (blockIdx.x < MG_B) {
    // ---- mgemm<128, no BN, fp32 A, no dinv> ----
    int wid  = (blockIdx.x * 256 + threadIdx.x) >> 6;
    int lane = threadIdx.x & 63;
    if (wid >= NN / 32) return;
    const int m = lane & 31;
    const int q = lane >> 5;
    const int row0 = wid * 32;
    const float* Arow = x + (size_t)(row0 + m) * 128 + q * 8;

    floatx16 acc[4] = {};
#pragma unroll
    for (int s = 0; s < 8; ++s) {
      float4 a0 = *(const float4*)(Arow + 16 * s);
      float4 a1 = *(const float4*)(Arow + 16 * s + 4);
      half8 af;
      af[0] = (_Float16)a0.x; af[1] = (_Float16)a0.y;
      af[2] = (_Float16)a0.z; af[3] = (_Float16)a0.w;
      af[4] = (_Float16)a1.x; af[5] = (_Float16)a1.y;
      af[6] = (_Float16)a1.z; af[7] = (_Float16)a1.w;
#pragma unroll
      for (int ct = 0; ct < 4; ++ct) {
        half8 bf = *(const half8*)(Wt1 + (size_t)(ct * 32 + m) * 128 + q * 8 + 16 * s);
        acc[ct] = __builtin_amdgcn_mfma_f32_32x32x16_f16(af, bf, acc[ct], 0, 0, 0);
      }
    }
#pragma unroll
    for (int ct = 0; ct < 4; ++ct)
#pragma unroll
      for (int r = 0; r < 16; ++r) {
        int row = (r & 3) + 8 * (r >> 2) + 4 * q;   // C/D map [m74/m101]
        C[(size_t)(row0 + row) * 128 + ct * 32 + m] = (_Float16)acc[ct][r];
      }
  } else {
    int e = (blockIdx.x - MG_B) * 256 + threadIdx.x;
    if (e < NE) slot[e] = atomicAdd(&deg[dst[e]], 1);
  }
}

// ============================================================
// scan: deg -> exclusive rowptr (+dinv)
// ============================================================
__global__ __launch_bounds__(256) void k_scan_a(const int* __restrict__ deg,
                                                float* __restrict__ dinv,
                                                int* __restrict__ rowptr,
                                                int* __restrict__ bsum) {
  __shared__ int sd[256];
  int t = threadIdx.x;
  int i = blockIdx.x * 256 + t;
  int v = (i < NN) ? deg[i] : 0;
  if (i < NN) dinv[i] = rsqrtf((float)(v + 1));   // +1 self-loop
  sd[t] = v;
  __syncthreads();
  for (int off = 1; off < 256; off <<= 1) {
    int x = (t >= off) ? sd[t - off] : 0;
    __syncthreads();
    sd[t] += x;
    __syncthreads();
  }
  if (i < NN) rowptr[i] = sd[t] - v;              // exclusive
  if (t == 255) bsum[blockIdx.x] = sd[255];
}

__global__ __launch_bounds__(512) void k_scan_b(int* __restrict__ bsum, int nb) {
  __shared__ int sd[512];
  int t = threadIdx.x;
  int v = (t < nb) ? bsum[t] : 0;
  sd[t] = v;
  __syncthreads();
  for (int off = 1; off < 512; off <<= 1) {
    int x = (t >= off) ? sd[t - off] : 0;
    __syncthreads();
    sd[t] += x;
    __syncthreads();
  }
  if (t < nb) bsum[t] = sd[t] - v;                // exclusive block offsets
}

__global__ __launch_bounds__(256) void k_scan_c(int* __restrict__ rowptr,
                                                const int* __restrict__ bsum) {
  int i = blockIdx.x * 256 + threadIdx.x;
  if (i < NN) rowptr[i] += bsum[blockIdx.x];
  if (i == 0) rowptr[NN] = NE;
}

// ============================================================
// F2: fused  [blocks 0..SC_B)        : Hf[r,:] *= dinv[r] (in place, fp32 math)
//            [SC_B..SC_B+CNT_B)      : CSR fill (atomic-free scatter)
// scaleH (~10 us of bytes) hides under fill's scatter (~90 us).
// ============================================================
__global__ __launch_bounds__(256) void k_f2(const int* __restrict__ ei,
                                            const int* __restrict__ rowptr,
                                            const int* __restrict__ slot,
                                            int* __restrict__ csrc,
                                            const float* __restrict__ dinv,
                                            uint2* __restrict__ Hf) {
  if (blockIdx.x < SC_B) {
    int i = blockIdx.x * 256 + threadIdx.x;   // uint2 index = 4 halves
    int row = i >> 5;                         // 32 uint2 per 128-col row
    float dv = dinv[row];
    uint2 v = Hf[i];
    __half2 h0 = *(__half2*)&v.x;
    __half2 h1 = *(__half2*)&v.y;
    float2 f0 = __half22float2(h0);
    float2 f1 = __half22float2(h1);
    h0 = __floats2half2_rn(f0.x * dv, f0.y * dv);
    h1 = __floats2half2_rn(f1.x * dv, f1.y * dv);
    v.x = *(unsigned*)&h0;
    v.y = *(unsigned*)&h1;
    Hf[i] = v;
  } else {
    int e = (blockIdx.x - SC_B) * 256 + threadIdx.x;
    if (e >= NE) return;
    int s = ei[e];            // edge_index[0] = src
    int d = ei[NE + e];       // edge_index[1] = dst
    csrc[rowptr[d] + slot[e]] = s;
  }
}

// ============================================================
// MFMA f16 GEMM (register-only, no LDS), layers 2/3:
// Ht[r,:] = fp16( dinv[r] * ( BNReLU(A[r,:]) @ W ) ), K=128, BN_ cols.
// ============================================================
template <int BN_>
__global__ __launch_bounds__(256) void k_mgemm(const _Float16* __restrict__ A,
                                               const _Float16* __restrict__ Wt,
                                               const float* __restrict__ scale,
                                               const float* __restrict__ shift,
                                               const float* __restrict__ dinv,
                                               _Float16* __restrict__ C) {
  constexpr int NCT = BN_ / 32;
  int wid  = (blockIdx.x * 256 + threadIdx.x) >> 6;
  int lane = threadIdx.x & 63;
  if (wid >= NN / 32) return;
  const int m = lane & 31;
  const int q = lane >> 5;
  const int row0 = wid * 32;

  const _Float16* Arow = A + (size_t)(row0 + m) * 128 + q * 8;

  floatx16 acc[NCT] = {};

#pragma unroll
  for (int s = 0; s < 8; ++s) {
    half8 raw = *(const half8*)(Arow + 16 * s);
    int k0 = 16 * s + q * 8;
    half8 af;
#pragma unroll
    for (int j = 0; j < 8; ++j) {
      float a = fmaxf(fmaf((float)raw[j], scale[k0 + j], shift[k0 + j]), 0.f);
      af[j] = (_Float16)a;
    }
#pragma unroll
    for (int ct = 0; ct < NCT; ++ct) {
      half8 bf = *(const half8*)(Wt + (size_t)(ct * 32 + m) * 128 + q * 8 + 16 * s);
      acc[ct] = __builtin_amdgcn_mfma_f32_32x32x16_f16(af, bf, acc[ct], 0, 0, 0);
    }
  }

#pragma unroll
  for (int ct = 0; ct < NCT; ++ct)
#pragma unroll
    for (int r = 0; r < 16; ++r) {
      int row = (r & 3) + 8 * (r >> 2) + 4 * q;
      float dv = dinv[row0 + row];
      C[(size_t)(row0 + row) * BN_ + ct * 32 + m] = (_Float16)(acc[ct][r] * dv);
    }
}

// ============================================================
// Pull aggregation, D=128 fp16 -> fp16 (fp32 accumulate)
// ============================================================
__global__ __launch_bounds__(256) void k_agg128(const __half* __restrict__ H,
                                                const float* __restrict__ dinv,
                                                const int* __restrict__ rowptr,
                                                const int* __restrict__ srcs,
                                                __half2* __restrict__ out) {
  int wid  = (blockIdx.x * 256 + threadIdx.x) >> 6;
  int lane = threadIdx.x & 63;
  if (wid >= NN) return;
  const __half2* Hp = (const __half2*)H;
  float2 acc = __half22float2(Hp[(size_t)wid * 64 + lane]);   // self term
  int beg = rowptr[wid], end = rowptr[wid + 1];
  int e = beg;
  int end8 = beg + ((end - beg) & ~7);
  for (; e < end8; e += 8) {
    __half2 v0 = Hp[(size_t)srcs[e+0] * 64 + lane];
    __half2 v1 = Hp[(size_t)srcs[e+1] * 64 + lane];
    __half2 v2 = Hp[(size_t)srcs[e+2] * 64 + lane];
    __half2 v3 = Hp[(size_t)srcs[e+3] * 64 + lane];
    __half2 v4 = Hp[(size_t)srcs[e+4] * 64 + lane];
    __half2 v5 = Hp[(size_t)srcs[e+5] * 64 + lane];
    __half2 v6 = Hp[(size_t)srcs[e+6] * 64 + lane];
    __half2 v7 = Hp[(size_t)srcs[e+7] * 64 + lane];
    float2 f0 = __half22float2(v0), f1 = __half22float2(v1);
    float2 f2 = __half22float2(v2), f3 = __half22float2(v3);
    float2 f4 = __half22float2(v4), f5 = __half22float2(v5);
    float2 f6 = __half22float2(v6), f7 = __half22float2(v7);
    acc.x += (f0.x + f1.x) + (f2.x + f3.x) + (f4.x + f5.x) + (f6.x + f7.x);
    acc.y += (f0.y + f1.y) + (f2.y + f3.y) + (f4.y + f5.y) + (f6.y + f7.y);
  }
  for (; e < end; ++e) {
    float2 f = __half22float2(Hp[(size_t)srcs[e] * 64 + lane]);
    acc.x += f.x; acc.y += f.y;
  }
  float di = dinv[wid];
  out[(size_t)wid * 64 + lane] = __floats2half2_rn(acc.x * di, acc.y * di);
}

// ============================================================
// Final layer: aggregation (D=64, fp16) + bias + softmax
// ============================================================
__global__ __launch_bounds__(256) void k_agg64_softmax(const __half* __restrict__ H,
                                                       const float* __restrict__ dinv,
                                                       const int* __restrict__ rowptr,
                                                       const int* __restrict__ srcs,
                                                       const float* __restrict__ b3,
                                                       float* __restrict__ out) {
  int wid  = (blockIdx.x * 256 + threadIdx.x) >> 6;
  int lane = threadIdx.x & 63;
  if (wid >= NN) return;
  float acc = __half2float(H[(size_t)wid * 64 + lane]);   // self term
  int beg = rowptr[wid], end = rowptr[wid + 1];
  int e = beg;
  int end8 = beg + ((end - beg) & ~7);
  for (; e < end8; e += 8) {
    float v0 = __half2float(H[(size_t)srcs[e+0] * 64 + lane]);
    float v1 = __half2float(H[(size_t)srcs[e+1] * 64 + lane]);
    float v2 = __half2float(H[(size_t)srcs[e+2] * 64 + lane]);
    float v3 = __half2float(H[(size_t)srcs[e+3] * 64 + lane]);
    float v4 = __half2float(H[(size_t)srcs[e+4] * 64 + lane]);
    float v5 = __half2float(H[(size_t)srcs[e+5] * 64 + lane]);
    float v6 = __half2float(H[(size_t)srcs[e+6] * 64 + lane]);
    float v7 = __half2float(H[(size_t)srcs[e+7] * 64 + lane]);
    acc += (v0 + v1) + (v2 + v3) + (v4 + v5) + (v6 + v7);
  }
  for (; e < end; ++e)
    acc += __half2float(H[(size_t)srcs[e] * 64 + lane]);
  acc = acc * dinv[wid] + b3[lane];

  float m = acc;
#pragma unroll
  for (int off = 32; off > 0; off >>= 1) m = fmaxf(m, __shfl_xor(m, off));
  float ev = __expf(acc - m);
  float s = ev;
#pragma unroll
  for (int off = 32; off > 0; off >>= 1) s += __shfl_xor(s, off);
  out[(size_t)wid * 64 + lane] = ev / s;
}

// ============================================================
// BatchNorm column stats over fp16 h (fp32 accumulate)
// ============================================================
__global__ __launch_bounds__(256) void k_stats(const __half2* __restrict__ H2,
                                               float* __restrict__ S1,
                                               float* __restrict__ S2) {
  int t = threadIdx.x;
  int p = t & 63;
  int r = t >> 6;
  float2 s1 = {0.f, 0.f}, s2 = {0.f, 0.f};
  for (int row = blockIdx.x * 4 + r; row < NN; row += gridDim.x * 4) {
    float2 v = __half22float2(H2[(size_t)row * 64 + p]);
    s1.x += v.x; s1.y += v.y;
    s2.x += v.x * v.x; s2.y += v.y * v.y;
  }
  __shared__ float2 l1[256], l2[256];
  l1[t] = s1; l2[t] = s2;
  __syncthreads();
  if (t < 128) {
    l1[t].x += l1[t+128].x; l1[t].y += l1[t+128].y;
    l2[t].x += l2[t+128].x; l2[t].y += l2[t+128].y;
  }
  __syncthreads();
  if (t < 64) {
    float2 a1 = l1[t], b1 = l1[t+64];
    float2 a2 = l2[t], b2 = l2[t+64];
    atomicAdd(&S1[2*p+0], a1.x + b1.x);
    atomicAdd(&S1[2*p+1], a1.y + b1.y);
    atomicAdd(&S2[2*p+0], a2.x + b2.x);
    atomicAdd(&S2[2*p+1], a2.y + b2.y);
  }
}

__global__ void k_finalize(const float* __restrict__ S1, const float* __restrict__ S2,
                           const float* __restrict__ g,  const float* __restrict__ be,
                           float* __restrict__ scale,    float* __restrict__ shift) {
  int t = threadIdx.x;  // 128 threads
  float mean = S1[t] * (1.0f / NN);
  float var  = S2[t] * (1.0f / NN) - mean * mean;
  float is   = rsqrtf(var + BN_EPS);
  float sc   = g[t] * is;
  scale[t] = sc;
  shift[t] = be[t] - mean * sc;
}

// ============================================================
// host launch
// ============================================================
extern "C" void kernel_launch(void* const* d_in, const int* in_sizes, int n_in,
                              void* d_out, int out_size, void* d_ws, size_t ws_size,
                              hipStream_t stream) {
  (void)in_sizes; (void)n_in; (void)out_size; (void)ws_size;
  const float* x   = (const float*)d_in[0];
  const int*   ei  = (const int*)d_in[1];
  const float* W1  = (const float*)d_in[2];
  // d_in[3] = b1: cancels in BatchNorm (constant column shift), skipped
  const float* W2  = (const float*)d_in[4];
  // d_in[5] = b2: same
  const float* W3  = (const float*)d_in[6];
  const float* b3  = (const float*)d_in[7];
  const float* g1  = (const float*)d_in[8];
  const float* be1 = (const float*)d_in[9];
  const float* g2  = (const float*)d_in[10];
  const float* be2 = (const float*)d_in[11];
  float* out = (float*)d_out;

  char* ws = (char*)d_ws;
  size_t off = 0;
  auto take = [&](size_t bytes) -> char* {
    char* p = ws + off;
    off = (off + bytes + 255) & ~(size_t)255;
    return p;
  };
  int*   deg    = (int*)  take((size_t)NN * 4);
  float* S1a    = (float*)take(128 * 4);
  float* S2a    = (float*)take(128 * 4);
  float* S1b    = (float*)take(128 * 4);
  float* S2b    = (float*)take(128 * 4);
  size_t zero_bytes = off;                  // deg + stats zeroed each call
  float* scale1 = (float*)take(128 * 4);
  float* shift1 = (float*)take(128 * 4);
  float* scale2 = (float*)take(128 * 4);
  float* shift2 = (float*)take(128 * 4);
  float* dinv   = (float*)take((size_t)NN * 4);
  int*   rowptr = (int*)  take((size_t)(NN + 1) * 4);
  int*   bsum   = (int*)  take(1024 * 4);
  int*   slot   = (int*)  take((size_t)NE * 4);
  int*   csrc   = (int*)  take((size_t)NE * 4);
  _Float16* Wt1 = (_Float16*)take((size_t)128 * 128 * 2);
  _Float16* Wt2 = (_Float16*)take((size_t)128 * 128 * 2);
  _Float16* Wt3 = (_Float16*)take((size_t)64 * 128 * 2);
  _Float16* Hf  = (_Float16*)take((size_t)NN * 128 * 2);  // fp16 gather table
  _Float16* hB  = (_Float16*)take((size_t)NN * 128 * 2);  // fp16 agg output

  (void)hipMemsetAsync(d_ws, 0, zero_bytes, stream);

  const int nbN  = (NN + 255) / 256;        // 391
  const int mgB  = MG_B;                    // 782
  const int aggB = (NN + 3) / 4;            // 25000

  k_wprep_all<<<160, 256, 0, stream>>>(W1, W2, W3, Wt1, Wt2, Wt3);

  // F1: layer-1 GEMM (unscaled) overlapped with degree count
  k_f1<<<MG_B + CNT_B, 256, 0, stream>>>(ei + NE, deg, slot, x, Wt1, Hf);

  k_scan_a<<<nbN, 256, 0, stream>>>(deg, dinv, rowptr, bsum);
  k_scan_b<<<1, 512, 0, stream>>>(bsum, nbN);
  k_scan_c<<<nbN, 256, 0, stream>>>(rowptr, bsum);

  // F2: dinv row-scale of Hf overlapped with CSR fill
  k_f2<<<SC_B + CNT_B, 256, 0, stream>>>(ei, rowptr, slot, csrc, dinv, (uint2*)Hf);

  // layer 1 tail
  k_agg128<<<aggB, 256, 0, stream>>>((const __half*)Hf, dinv, rowptr, csrc, (__half2*)hB);
  k_stats<<<1024, 256, 0, stream>>>((const __half2*)hB, S1a, S2a);
  k_finalize<<<1, 128, 0, stream>>>(S1a, S2a, g1, be1, scale1, shift1);

  // layer 2 (BN+ReLU fused into GEMM A-load)
  k_mgemm<128><<<mgB, 256, 0, stream>>>(hB, Wt2, scale1, shift1, dinv, Hf);
  k_agg128<<<aggB, 256, 0, stream>>>((const __half*)Hf, dinv, rowptr, csrc, (__half2*)hB);
  k_stats<<<1024, 256, 0, stream>>>((const __half2*)hB, S1b, S2b);
  k_finalize<<<1, 128, 0, stream>>>(S1b, S2b, g2, be2, scale2, shift2);

  // layer 3 (BN+ReLU fused) -> N x 64 fp16, then aggregation + bias + softmax
  k_mgemm<64><<<mgB, 256, 0, stream>>>(hB, Wt3, scale2, shift2, dinv, Hf);
  k_agg64_softmax<<<aggB, 256, 0, stream>>>((const __half*)Hf, dinv, rowptr, csrc, b3, out);
}